// Round 7
// baseline (564.392 us; speedup 1.0000x reference)
//
#include <hip/hip_runtime.h>
#include <cstddef>
#include <cstdint>

// Problem constants: EMBED=1024, NUM_HEADS=16, GQA=4, KV_HEADS=4,
// HEAD_DIM=64, KV_EMBED=256, EPS=1e-3, B=2, T=1024.
#define TSEQ 1024

typedef __attribute__((ext_vector_type(8))) short short8;   // 8 bf16 = 4 VGPRs
typedef __attribute__((ext_vector_type(4))) float floatx4;  // MFMA acc

// Workspace layout (floats):
//  XQ : 2048 x 1024  (2M)
//  XK : 2048 x 256   (0.5M)
//  XVt: 2 x 256 x 1024 (0.5M)  -- V-projection TRANSPOSED: [b][h*64+c][j]
//  XO : 2048 x 1024  (2M)
//  P  : 32 x 1024x1024 (33.55M) -- q=1-p / phi in GROUP-DIAGONAL layout
static constexpr size_t OFF_XQ  = 0;
static constexpr size_t OFF_XK  = (size_t)2 * 1024 * 1024;
static constexpr size_t OFF_XVT = OFF_XK + (size_t)512 * 1024;
static constexpr size_t OFF_XO  = OFF_XVT + (size_t)512 * 1024;
static constexpr size_t OFF_P   = OFF_XO + (size_t)2 * 1024 * 1024;

// GROUP-DIAGONAL LAYOUT (R10): logical cell (r, c) lives at storage row
//   diagrow(r, c>>4) = (((r>>2) + (c>>4)) & 255)*4 + (r&3).
// The recurrence kernel processes R=4 rows per step: lane t owns cols
// [16t,16t+16) and at step s handles row-group g = s - t (rows 4g..4g+3).
// All 64 lanes' cells for one step live in ONE contiguous 16KB slot
// (slot = s & 255), read and overwritten in place. Wrap bijection: at step
// m the writers are lanes t <= m; at step m+256 the readers of that slot
// are lanes t >= m+1 -- disjoint. Scores (CDIAG) writes and PV (ADIAG)
// reads through the same map; per-instruction coalescing is preserved.
//
// R11: q-form (scores stores q = 1-p): chain fma + carry fma, no subs.
// R12 diagnosis: R11 measured 1850 cy/step = ~450 issue + ~1300 STALL.
//  (a) VGPR_Count=92 < 128 floats of pA+pB -> compiler SANK the prefetch
//      loads to their use (double buffer collapsed; full load latency
//      exposed every step). Fix: sched_barrier(0) pins the load block.
//  (b) single phi[16] reused by 4 rows/step: global stores read VGPRs
//      async (vmcnt); rewriting them next row = wait on NEWEST vmem op
//      = vmcnt(0) FULL DRAIN, 4x/step. Fix: phim[4][16] + stores batched
//      at step end -> WAW distance = 1 step, wait becomes vmcnt(16) on
//      the oldest entries (cheap). Also retro-explains R8's flat result.

// ---------------------------------------------------------------------------
// fp32 -> bf16 hi/lo split (RNE). x ≈ hi + lo with residual ~2^-17 |x|.
// ---------------------------------------------------------------------------
__device__ __forceinline__ void cvt_hi_lo(float x, unsigned short& hi,
                                          unsigned short& lo) {
  unsigned u = __float_as_uint(x);
  unsigned rh = (u + 0x7FFFu + ((u >> 16) & 1u)) & 0xFFFF0000u;
  hi = (unsigned short)(rh >> 16);
  float xl = x - __uint_as_float(rh);
  unsigned ul = __float_as_uint(xl);
  unsigned rl = ul + 0x7FFFu + ((ul >> 16) & 1u);
  lo = (unsigned short)(rl >> 16);
}

__device__ __forceinline__ int diagrow(int r, int cblk) {
  return ((((r >> 2) + cblk) & 255) << 2) | (r & 3);
}

// ---------------------------------------------------------------------------
// Unified NT GEMM core, MFMA bf16x3 (R5-proven).
// ADIAG: A row index mapped through diagrow (reads group-diagonal matrix).
// CDIAG: C row index mapped through diagrow (writes group-diagonal matrix).
// EPI=2 writes q = sigmoid(-x) clipped (R11).
// ---------------------------------------------------------------------------
template <int EPI, int ADIAG, int CDIAG>
__device__ __forceinline__ void mfma_nt_core(
    const float* __restrict__ A, int lda,
    const float* __restrict__ B, int ldb,
    float* __restrict__ C, int ldc, int K,
    const float* __restrict__ bias)
{
  __shared__ __align__(16) unsigned short Ah[64][40];
  __shared__ __align__(16) unsigned short Al[64][40];
  __shared__ __align__(16) unsigned short Bh[64][40];
  __shared__ __align__(16) unsigned short Bl[64][40];

  const int bm = blockIdx.y << 6;
  const int bn = blockIdx.x << 6;
  const int tid  = threadIdx.x;
  const int lane = tid & 63;
  const int wave = tid >> 6;        // 0..3 -> row sub-tile
  const int m16  = lane & 15;
  const int quad = lane >> 4;

  const int srow = tid >> 2;        // staging: row 0..63
  const int skq  = (tid & 3) << 3;  // staging: k offset 0,8,16,24

  floatx4 acc[4];
#pragma unroll
  for (int c = 0; c < 4; ++c) acc[c] = (floatx4){0.f, 0.f, 0.f, 0.f};

  for (int k0 = 0; k0 < K; k0 += 32) {
    {
      const int kq = k0 + skq;
      int arow = bm + srow;
      if (ADIAG) arow = diagrow(arow, kq >> 4);
      const float* ap = A + (size_t)arow * lda + kq;
      const float* bp = B + (size_t)(bn + srow) * ldb + kq;
      float av[8] __attribute__((aligned(16)));
      float bv[8] __attribute__((aligned(16)));
      *(float4*)&av[0] = *(const float4*)(ap);
      *(float4*)&av[4] = *(const float4*)(ap + 4);
      *(float4*)&bv[0] = *(const float4*)(bp);
      *(float4*)&bv[4] = *(const float4*)(bp + 4);
      short8 vah, valo, vbh, vblo;
#pragma unroll
      for (int e = 0; e < 8; ++e) {
        unsigned short h, l;
        cvt_hi_lo(av[e], h, l);
        vah[e] = (short)h; valo[e] = (short)l;
        cvt_hi_lo(bv[e], h, l);
        vbh[e] = (short)h; vblo[e] = (short)l;
      }
      *(short8*)&Ah[srow][skq] = vah;
      *(short8*)&Al[srow][skq] = valo;
      *(short8*)&Bh[srow][skq] = vbh;
      *(short8*)&Bl[srow][skq] = vblo;
    }
    __syncthreads();

    const int arow = (wave << 4) + m16;
    const short8 a_h = *(const short8*)&Ah[arow][quad << 3];
    const short8 a_l = *(const short8*)&Al[arow][quad << 3];
#pragma unroll
    for (int c = 0; c < 4; ++c) {
      const int brow = (c << 4) + m16;
      const short8 b_h = *(const short8*)&Bh[brow][quad << 3];
      const short8 b_l = *(const short8*)&Bl[brow][quad << 3];
      acc[c] = __builtin_amdgcn_mfma_f32_16x16x32_bf16(a_h, b_h, acc[c], 0, 0, 0);
      acc[c] = __builtin_amdgcn_mfma_f32_16x16x32_bf16(a_h, b_l, acc[c], 0, 0, 0);
      acc[c] = __builtin_amdgcn_mfma_f32_16x16x32_bf16(a_l, b_h, acc[c], 0, 0, 0);
    }
    __syncthreads();
  }

#pragma unroll
  for (int c = 0; c < 4; ++c) {
#pragma unroll
    for (int r = 0; r < 4; ++r) {
      const int row = (wave << 4) + (quad << 2) + r;
      const int col = (c << 4) + m16;
      float v = acc[c][r];
      if (EPI == 0) { if (bias) v += bias[bn + col]; }
      if (EPI == 1) { v += bias[bm + row]; }
      if (EPI == 2) {
        // q = 1 - clip(sigmoid(v)) = clip(sigmoid(-v), 0.001, 0.999)
        v = 1.0f / (1.0f + expf(v));
        v = fminf(fmaxf(v, 0.001f), 0.999f);
      }
      int crow = bm + row;
      if (CDIAG) crow = diagrow(crow, (bn + col) >> 4);
      C[(size_t)crow * ldc + (bn + col)] = v;
    }
  }
}

__global__ __launch_bounds__(256) void gemm_nt_mfma_k(
    const float* __restrict__ A, int lda, const float* __restrict__ W, int ldw,
    const float* __restrict__ bias, float* __restrict__ C, int ldc, int K)
{
  mfma_nt_core<0, 0, 0>(A, lda, W, ldw, C, ldc, K, bias);
}

__global__ __launch_bounds__(256) void proj_vt_k(
    const float* __restrict__ vw, const float* __restrict__ value,
    const float* __restrict__ vb, float* __restrict__ XVt)
{
  const int b = blockIdx.z;
  mfma_nt_core<1, 0, 0>(vw, 1024, value + ((size_t)b << 20), 1024,
                        XVt + (size_t)b * 256 * 1024, 1024, 1024, vb);
}

// scores: writes q = 1-p in GROUP-DIAGONAL layout (CDIAG=1)
__global__ __launch_bounds__(256) void scores_mfma_k(
    const float* __restrict__ XQ, const float* __restrict__ XK,
    float* __restrict__ P)
{
  const int z = blockIdx.z;
  const int b = z >> 4;
  mfma_nt_core<2, 0, 1>(XQ + ((size_t)b << 20) + ((size_t)(z & 15) << 6), 1024,
                        XK + (size_t)b * TSEQ * 256 + ((size_t)(z & 3) << 6), 256,
                        P + ((size_t)z << 20), 1024, 64, nullptr);
}

// pv: reads phi (A matrix) from GROUP-DIAGONAL layout (ADIAG=1)
__global__ __launch_bounds__(256) void pv_mfma_k(
    const float* __restrict__ P, const float* __restrict__ XVt,
    float* __restrict__ XO)
{
  const int z = blockIdx.z;
  const int b = z >> 4;
  mfma_nt_core<0, 1, 0>(P + ((size_t)z << 20), 1024,
                        XVt + (size_t)b * 256 * 1024 + (size_t)(z & 3) * 64 * 1024, 1024,
                        XO + ((size_t)b << 20) + ((size_t)(z & 15) << 6), 1024,
                        1024, nullptr);
}

// ---------------------------------------------------------------------------
// Monotonic recurrence, 4-ROW diagonal wavefront, q-form, de-stalled (R12).
// ONE WAVE per z. Lane t owns cols [16t,16t+16); at step s handles row-group
// g = s - t (rows 4g..4g+3):
//   phi[r,c] = b[c] + q[r,c-1]*phi[r,c-1]        (1 fma)
//   b[c]     = fma(-q[r,c], phi[r,c], phi[r,c])  (= phi*p, 1 fma)
// Cross-lane: ONE batch of 8 __shfl_up(.,1) per step (phi15/q15 x 4 rows).
// R12: (a) prefetch block pinned at step top via sched_barrier(0) so the
// compiler cannot sink it (keeps pA/pB both live -> true 1-step-ahead
// prefetch); (b) per-row phim[4][16] with ALL stores batched at step end
// (store-WAW reuse distance = 1 full step; no per-row vmcnt(0) drains).
// Cross-lane = __shfl only (DPP failed 3x on gfx950 -- permanently banned).
// ---------------------------------------------------------------------------
__global__ __launch_bounds__(64) void mono_rec_k(float* __restrict__ P)
{
  const int z = blockIdx.x;
  float* __restrict__ Pz = P + ((size_t)z << 20);
  const int t = threadIdx.x;     // lane 0..63
  const int col0 = t << 4;       // first owned column

  float b[16];                   // carry: b[c] = phi[r-1,c] * p[r-1,c]
#pragma unroll
  for (int c = 0; c < 16; ++c) b[c] = 0.0f;
  float phi15h[4], q15h[4];      // col-15 values of the 4 rows, for lane t+1
#pragma unroll
  for (int k = 0; k < 4; ++k) { phi15h[k] = 0.0f; q15h[k] = 0.0f; }

  float pA[4][16], pB[4][16];    // q ping-pong (4 rows x 16 cols)

  // prologue: load slot 0 into pA
#pragma unroll
  for (int k = 0; k < 4; ++k) {
    const float* lp = Pz + (k << 10) + col0;
#pragma unroll
    for (int q = 0; q < 4; ++q)
      *(float4*)&pA[k][4 * q] = *(const float4*)(lp + 4 * q);
  }

  auto step = [&](int s, float (&pcur)[4][16], float (&pnext)[4][16]) {
    // prefetch next step's slot FIRST (never aliases in-flight stores:
    // slots s-1, s vs (s+1)&255 are distinct; wrap-overlap lanes invalid)
    {
      const float* np = Pz + ((size_t)((s + 1) & 255) << 12) + col0;
#pragma unroll
      for (int k = 0; k < 4; ++k)
#pragma unroll
        for (int q = 0; q < 4; ++q)
          *(float4*)&pnext[k][4 * q] = *(const float4*)(np + (k << 10) + 4 * q);
    }
    // pin the prefetch here: compiler may not sink these loads to their
    // use site (which would collapse the double buffer -- R12 diagnosis a).
    __builtin_amdgcn_sched_barrier(0);

    // boundary batch from lane t-1 (its rows' col 16t-1, finished at s-1).
    // Unconditional so source lanes are active in the shuffle.
    float phiL[4], qL[4];
#pragma unroll
    for (int k = 0; k < 4; ++k) {
      phiL[k] = __shfl_up(phi15h[k], 1);
      qL[k]   = __shfl_up(q15h[k], 1);
    }

    const int g = s - t;
    if (g >= 0 && g < 256) {
      float phim[4][16];         // per-row phi (R12 diagnosis b)
#pragma unroll
      for (int k = 0; k < 4; ++k) {
        const float* qk = pcur[k];
        float* phi = phim[k];
        if (g == 0 && k == 0) {
          // row 0: phi = onehot(col 0)
#pragma unroll
          for (int c = 0; c < 16; ++c) phi[c] = 0.0f;
          if (t == 0) phi[0] = 1.0f;
        } else {
          const float H0 = (t == 0) ? 0.0f : qL[k];
          float x = fmaf(H0, phiL[k], b[0]);
          phi[0] = x;
#pragma unroll
          for (int c = 1; c < 16; ++c) {
            x = fmaf(qk[c - 1], x, b[c]);
            phi[c] = x;
          }
        }
        // carry for next row (b = phi*p = phi - q*phi) + neighbor holds
#pragma unroll
        for (int c = 0; c < 16; ++c) b[c] = fmaf(-qk[c], phi[c], phi[c]);
        q15h[k]   = qk[15];
        phi15h[k] = phi[15];
      }
      // ALL stores batched at step end (in-place, coalesced). The data
      // VGPRs (phim) are not rewritten until this point next step.
      float* sp = Pz + ((size_t)(s & 255) << 12) + col0;
#pragma unroll
      for (int k = 0; k < 4; ++k)
#pragma unroll
        for (int q = 0; q < 4; ++q)
          *(float4*)(sp + (k << 10) + 4 * q) = *(float4*)&phim[k][4 * q];
    }
  };

  for (int s0 = 0; s0 < 320; s0 += 2) {
    step(s0, pA, pB);
    step(s0 + 1, pB, pA);
  }
}

// ---------------------------------------------------------------------------
extern "C" void kernel_launch(void* const* d_in, const int* in_sizes, int n_in,
                              void* d_out, int out_size, void* d_ws, size_t ws_size,
                              hipStream_t stream)
{
  const float* query = (const float*)d_in[0];
  const float* key   = (const float*)d_in[1];
  const float* value = (const float*)d_in[2];
  const float* ipw   = (const float*)d_in[3];   // (1536,1024)
  const float* ipb   = (const float*)d_in[4];   // (1536,)
  const float* opw   = (const float*)d_in[5];   // (1024,1024)
  const float* opb   = (const float*)d_in[6];   // (1024,)
  float* out = (float*)d_out;
  float* ws  = (float*)d_ws;

  float* XQ  = ws + OFF_XQ;
  float* XK  = ws + OFF_XK;
  float* XVt = ws + OFF_XVT;
  float* XO  = ws + OFF_XO;
  float* P   = ws + OFF_P;

  // in-projections (MFMA bf16x3)
  gemm_nt_mfma_k<<<dim3(16, 32), 256, 0, stream>>>(
      query, 1024, ipw, 1024, ipb, XQ, 1024, 1024);
  gemm_nt_mfma_k<<<dim3(4, 32), 256, 0, stream>>>(
      key, 1024, ipw + (size_t)1024 * 1024, 1024, ipb + 1024, XK, 256, 1024);
  proj_vt_k<<<dim3(16, 4, 2), 256, 0, stream>>>(
      ipw + (size_t)1280 * 1024, value, ipb + 1280, XVt);

  // scores + sigmoid + clip -> q = 1-p (group-diagonal layout)
  scores_mfma_k<<<dim3(16, 16, 32), 256, 0, stream>>>(XQ, XK, P);

  // monotonic recurrence in place (4-row diagonal wavefront, q-form,
  // pinned prefetch + batched stores)
  mono_rec_k<<<dim3(32), dim3(64), 0, stream>>>(P);

  // phi @ V -> XO (NT against transposed V; A read through diagonal map)
  pv_mfma_k<<<dim3(1, 16, 32), 256, 0, stream>>>(P, XVt, XO);

  // out-projection
  gemm_nt_mfma_k<<<dim3(16, 32), 256, 0, stream>>>(
      XO, 1024, opw, 1024, opb, out, 1024, 1024);
}

// Round 8
// 562.443 us; speedup vs baseline: 1.0035x; 1.0035x over previous
//
#include <hip/hip_runtime.h>
#include <cstddef>
#include <cstdint>

// Problem constants: EMBED=1024, NUM_HEADS=16, GQA=4, KV_HEADS=4,
// HEAD_DIM=64, KV_EMBED=256, EPS=1e-3, B=2, T=1024.
#define TSEQ 1024

typedef __attribute__((ext_vector_type(8))) short short8;   // 8 bf16 = 4 VGPRs
typedef __attribute__((ext_vector_type(4))) float floatx4;  // MFMA acc

// Workspace layout (floats):
//  XQ : 2048 x 1024  (2M)
//  XK : 2048 x 256   (0.5M)
//  XVt: 2 x 256 x 1024 (0.5M)  -- V-projection TRANSPOSED: [b][h*64+c][j]
//  XO : 2048 x 1024  (2M)
//  P  : 32 x 1024x1024 (33.55M) -- q=1-p / phi in GROUP-DIAGONAL layout
static constexpr size_t OFF_XQ  = 0;
static constexpr size_t OFF_XK  = (size_t)2 * 1024 * 1024;
static constexpr size_t OFF_XVT = OFF_XK + (size_t)512 * 1024;
static constexpr size_t OFF_XO  = OFF_XVT + (size_t)512 * 1024;
static constexpr size_t OFF_P   = OFF_XO + (size_t)2 * 1024 * 1024;

// GROUP-DIAGONAL LAYOUT (R10): logical cell (r, c) lives at storage row
//   diagrow(r, c>>4) = (((r>>2) + (c>>4)) & 255)*4 + (r&3).
// R=4 rows per step: lane t owns cols [16t,16t+16), at step s handles
// row-group g = s - t (rows 4g..4g+3). One step = one contiguous 16KB slot
// (slot = s & 255), read and overwritten in place. Wrap bijection: slot
// readers at step m+256 are lanes t>m; its writers at step m were lanes
// t<=m; each lane owns a private 64B block -> reads and writes are BYTE-
// DISJOINT at runtime, always.
//
// R13: that disjointness is exposed to the compiler by passing the SAME
// buffer as (const float* __restrict__ Pin, float* __restrict__ Pout).
// Diagnosis chain: R7/R8/R11/R12 all showed ~1300cy/step of stall that
// survived every load-path and store-pattern change; the one invariant
// was stores and loads on the same pointer -> compiler emits a
// conservative store-drain s_waitcnt before each step's prefetch (no HW
// store->load forwarding on CDNA; ordering is compiler-inserted). With
// restrict the ordering edge disappears and the 1-step prefetch distance
// (~500cy of compute+store issue) actually hides the read latency.
// R11: q-form (scores stores q = 1-p): chain fma + carry fma, no subs.
// R12 (kept): prefetch pinned via sched_barrier(0); per-row phim[4][16]
// with stores batched at step end.

// ---------------------------------------------------------------------------
// fp32 -> bf16 hi/lo split (RNE). x ≈ hi + lo with residual ~2^-17 |x|.
// ---------------------------------------------------------------------------
__device__ __forceinline__ void cvt_hi_lo(float x, unsigned short& hi,
                                          unsigned short& lo) {
  unsigned u = __float_as_uint(x);
  unsigned rh = (u + 0x7FFFu + ((u >> 16) & 1u)) & 0xFFFF0000u;
  hi = (unsigned short)(rh >> 16);
  float xl = x - __uint_as_float(rh);
  unsigned ul = __float_as_uint(xl);
  unsigned rl = ul + 0x7FFFu + ((ul >> 16) & 1u);
  lo = (unsigned short)(rl >> 16);
}

__device__ __forceinline__ int diagrow(int r, int cblk) {
  return ((((r >> 2) + cblk) & 255) << 2) | (r & 3);
}

// ---------------------------------------------------------------------------
// Unified NT GEMM core, MFMA bf16x3 (R5-proven).
// ADIAG: A row index mapped through diagrow (reads group-diagonal matrix).
// CDIAG: C row index mapped through diagrow (writes group-diagonal matrix).
// EPI=2 writes q = sigmoid(-x) clipped (R11).
// ---------------------------------------------------------------------------
template <int EPI, int ADIAG, int CDIAG>
__device__ __forceinline__ void mfma_nt_core(
    const float* __restrict__ A, int lda,
    const float* __restrict__ B, int ldb,
    float* __restrict__ C, int ldc, int K,
    const float* __restrict__ bias)
{
  __shared__ __align__(16) unsigned short Ah[64][40];
  __shared__ __align__(16) unsigned short Al[64][40];
  __shared__ __align__(16) unsigned short Bh[64][40];
  __shared__ __align__(16) unsigned short Bl[64][40];

  const int bm = blockIdx.y << 6;
  const int bn = blockIdx.x << 6;
  const int tid  = threadIdx.x;
  const int lane = tid & 63;
  const int wave = tid >> 6;        // 0..3 -> row sub-tile
  const int m16  = lane & 15;
  const int quad = lane >> 4;

  const int srow = tid >> 2;        // staging: row 0..63
  const int skq  = (tid & 3) << 3;  // staging: k offset 0,8,16,24

  floatx4 acc[4];
#pragma unroll
  for (int c = 0; c < 4; ++c) acc[c] = (floatx4){0.f, 0.f, 0.f, 0.f};

  for (int k0 = 0; k0 < K; k0 += 32) {
    {
      const int kq = k0 + skq;
      int arow = bm + srow;
      if (ADIAG) arow = diagrow(arow, kq >> 4);
      const float* ap = A + (size_t)arow * lda + kq;
      const float* bp = B + (size_t)(bn + srow) * ldb + kq;
      float av[8] __attribute__((aligned(16)));
      float bv[8] __attribute__((aligned(16)));
      *(float4*)&av[0] = *(const float4*)(ap);
      *(float4*)&av[4] = *(const float4*)(ap + 4);
      *(float4*)&bv[0] = *(const float4*)(bp);
      *(float4*)&bv[4] = *(const float4*)(bp + 4);
      short8 vah, valo, vbh, vblo;
#pragma unroll
      for (int e = 0; e < 8; ++e) {
        unsigned short h, l;
        cvt_hi_lo(av[e], h, l);
        vah[e] = (short)h; valo[e] = (short)l;
        cvt_hi_lo(bv[e], h, l);
        vbh[e] = (short)h; vblo[e] = (short)l;
      }
      *(short8*)&Ah[srow][skq] = vah;
      *(short8*)&Al[srow][skq] = valo;
      *(short8*)&Bh[srow][skq] = vbh;
      *(short8*)&Bl[srow][skq] = vblo;
    }
    __syncthreads();

    const int arow = (wave << 4) + m16;
    const short8 a_h = *(const short8*)&Ah[arow][quad << 3];
    const short8 a_l = *(const short8*)&Al[arow][quad << 3];
#pragma unroll
    for (int c = 0; c < 4; ++c) {
      const int brow = (c << 4) + m16;
      const short8 b_h = *(const short8*)&Bh[brow][quad << 3];
      const short8 b_l = *(const short8*)&Bl[brow][quad << 3];
      acc[c] = __builtin_amdgcn_mfma_f32_16x16x32_bf16(a_h, b_h, acc[c], 0, 0, 0);
      acc[c] = __builtin_amdgcn_mfma_f32_16x16x32_bf16(a_h, b_l, acc[c], 0, 0, 0);
      acc[c] = __builtin_amdgcn_mfma_f32_16x16x32_bf16(a_l, b_h, acc[c], 0, 0, 0);
    }
    __syncthreads();
  }

#pragma unroll
  for (int c = 0; c < 4; ++c) {
#pragma unroll
    for (int r = 0; r < 4; ++r) {
      const int row = (wave << 4) + (quad << 2) + r;
      const int col = (c << 4) + m16;
      float v = acc[c][r];
      if (EPI == 0) { if (bias) v += bias[bn + col]; }
      if (EPI == 1) { v += bias[bm + row]; }
      if (EPI == 2) {
        // q = 1 - clip(sigmoid(v)) = clip(sigmoid(-v), 0.001, 0.999)
        v = 1.0f / (1.0f + expf(v));
        v = fminf(fmaxf(v, 0.001f), 0.999f);
      }
      int crow = bm + row;
      if (CDIAG) crow = diagrow(crow, (bn + col) >> 4);
      C[(size_t)crow * ldc + (bn + col)] = v;
    }
  }
}

__global__ __launch_bounds__(256) void gemm_nt_mfma_k(
    const float* __restrict__ A, int lda, const float* __restrict__ W, int ldw,
    const float* __restrict__ bias, float* __restrict__ C, int ldc, int K)
{
  mfma_nt_core<0, 0, 0>(A, lda, W, ldw, C, ldc, K, bias);
}

__global__ __launch_bounds__(256) void proj_vt_k(
    const float* __restrict__ vw, const float* __restrict__ value,
    const float* __restrict__ vb, float* __restrict__ XVt)
{
  const int b = blockIdx.z;
  mfma_nt_core<1, 0, 0>(vw, 1024, value + ((size_t)b << 20), 1024,
                        XVt + (size_t)b * 256 * 1024, 1024, 1024, vb);
}

// scores: writes q = 1-p in GROUP-DIAGONAL layout (CDIAG=1)
__global__ __launch_bounds__(256) void scores_mfma_k(
    const float* __restrict__ XQ, const float* __restrict__ XK,
    float* __restrict__ P)
{
  const int z = blockIdx.z;
  const int b = z >> 4;
  mfma_nt_core<2, 0, 1>(XQ + ((size_t)b << 20) + ((size_t)(z & 15) << 6), 1024,
                        XK + (size_t)b * TSEQ * 256 + ((size_t)(z & 3) << 6), 256,
                        P + ((size_t)z << 20), 1024, 64, nullptr);
}

// pv: reads phi (A matrix) from GROUP-DIAGONAL layout (ADIAG=1)
__global__ __launch_bounds__(256) void pv_mfma_k(
    const float* __restrict__ P, const float* __restrict__ XVt,
    float* __restrict__ XO)
{
  const int z = blockIdx.z;
  const int b = z >> 4;
  mfma_nt_core<0, 1, 0>(P + ((size_t)z << 20), 1024,
                        XVt + (size_t)b * 256 * 1024 + (size_t)(z & 3) * 64 * 1024, 1024,
                        XO + ((size_t)b << 20) + ((size_t)(z & 15) << 6), 1024,
                        1024, nullptr);
}

// ---------------------------------------------------------------------------
// Monotonic recurrence, 4-ROW diagonal wavefront, q-form, RESTRICT-SPLIT
// read/write views (R13). ONE WAVE per z. Pin and Pout receive the SAME
// device pointer; the group-diagonal wrap bijection guarantees the read
// and write sets are byte-disjoint at runtime (see layout comment), so
// the restrict views are semantically clean and remove the compiler's
// conservative store->load s_waitcnt serialization (R13 diagnosis).
//   phi[r,c] = b[c] + q[r,c-1]*phi[r,c-1]        (1 fma)
//   b[c]     = fma(-q[r,c], phi[r,c], phi[r,c])  (= phi*p, 1 fma)
// Cross-lane: ONE batch of 8 __shfl_up(.,1) per step (phi15/q15 x 4 rows).
// Cross-lane = __shfl only (DPP failed 3x on gfx950 -- permanently banned).
// ---------------------------------------------------------------------------
__global__ __launch_bounds__(64) void mono_rec_k(
    const float* __restrict__ Pin, float* __restrict__ Pout)
{
  const int z = blockIdx.x;
  const float* __restrict__ Pzr = Pin  + ((size_t)z << 20);
  float* __restrict__       Pzw = Pout + ((size_t)z << 20);
  const int t = threadIdx.x;     // lane 0..63
  const int col0 = t << 4;       // first owned column

  float b[16];                   // carry: b[c] = phi[r-1,c] * p[r-1,c]
#pragma unroll
  for (int c = 0; c < 16; ++c) b[c] = 0.0f;
  float phi15h[4], q15h[4];      // col-15 values of the 4 rows, for lane t+1
#pragma unroll
  for (int k = 0; k < 4; ++k) { phi15h[k] = 0.0f; q15h[k] = 0.0f; }

  float pA[4][16], pB[4][16];    // q ping-pong (4 rows x 16 cols)

  // prologue: load slot 0 into pA
#pragma unroll
  for (int k = 0; k < 4; ++k) {
    const float* lp = Pzr + (k << 10) + col0;
#pragma unroll
    for (int q = 0; q < 4; ++q)
      *(float4*)&pA[k][4 * q] = *(const float4*)(lp + 4 * q);
  }

  auto step = [&](int s, float (&pcur)[4][16], float (&pnext)[4][16]) {
    // prefetch next step's slot (restrict: issues without store ordering)
    {
      const float* np = Pzr + ((size_t)((s + 1) & 255) << 12) + col0;
#pragma unroll
      for (int k = 0; k < 4; ++k)
#pragma unroll
        for (int q = 0; q < 4; ++q)
          *(float4*)&pnext[k][4 * q] = *(const float4*)(np + (k << 10) + 4 * q);
    }
    // pin the prefetch: compiler may not sink these loads to their use
    // site (which would collapse the double buffer).
    __builtin_amdgcn_sched_barrier(0);

    // boundary batch from lane t-1 (its rows' col 16t-1, finished at s-1).
    // Unconditional so source lanes are active in the shuffle.
    float phiL[4], qL[4];
#pragma unroll
    for (int k = 0; k < 4; ++k) {
      phiL[k] = __shfl_up(phi15h[k], 1);
      qL[k]   = __shfl_up(q15h[k], 1);
    }

    const int g = s - t;
    if (g >= 0 && g < 256) {
      float phim[4][16];         // per-row phi (stores batched below)
#pragma unroll
      for (int k = 0; k < 4; ++k) {
        const float* qk = pcur[k];
        float* phi = phim[k];
        if (g == 0 && k == 0) {
          // row 0: phi = onehot(col 0)
#pragma unroll
          for (int c = 0; c < 16; ++c) phi[c] = 0.0f;
          if (t == 0) phi[0] = 1.0f;
        } else {
          const float H0 = (t == 0) ? 0.0f : qL[k];
          float x = fmaf(H0, phiL[k], b[0]);
          phi[0] = x;
#pragma unroll
          for (int c = 1; c < 16; ++c) {
            x = fmaf(qk[c - 1], x, b[c]);
            phi[c] = x;
          }
        }
        // carry for next row (b = phi*p = phi - q*phi) + neighbor holds
#pragma unroll
        for (int c = 0; c < 16; ++c) b[c] = fmaf(-qk[c], phi[c], phi[c]);
        q15h[k]   = qk[15];
        phi15h[k] = phi[15];
      }
      // stores batched at step end (in-place slot overwrite, coalesced)
      float* sp = Pzw + ((size_t)(s & 255) << 12) + col0;
#pragma unroll
      for (int k = 0; k < 4; ++k)
#pragma unroll
        for (int q = 0; q < 4; ++q)
          *(float4*)(sp + (k << 10) + 4 * q) = *(float4*)&phim[k][4 * q];
    }
  };

  for (int s0 = 0; s0 < 320; s0 += 2) {
    step(s0, pA, pB);
    step(s0 + 1, pB, pA);
  }
}

// ---------------------------------------------------------------------------
extern "C" void kernel_launch(void* const* d_in, const int* in_sizes, int n_in,
                              void* d_out, int out_size, void* d_ws, size_t ws_size,
                              hipStream_t stream)
{
  const float* query = (const float*)d_in[0];
  const float* key   = (const float*)d_in[1];
  const float* value = (const float*)d_in[2];
  const float* ipw   = (const float*)d_in[3];   // (1536,1024)
  const float* ipb   = (const float*)d_in[4];   // (1536,)
  const float* opw   = (const float*)d_in[5];   // (1024,1024)
  const float* opb   = (const float*)d_in[6];   // (1024,)
  float* out = (float*)d_out;
  float* ws  = (float*)d_ws;

  float* XQ  = ws + OFF_XQ;
  float* XK  = ws + OFF_XK;
  float* XVt = ws + OFF_XVT;
  float* XO  = ws + OFF_XO;
  float* P   = ws + OFF_P;

  // in-projections (MFMA bf16x3)
  gemm_nt_mfma_k<<<dim3(16, 32), 256, 0, stream>>>(
      query, 1024, ipw, 1024, ipb, XQ, 1024, 1024);
  gemm_nt_mfma_k<<<dim3(4, 32), 256, 0, stream>>>(
      key, 1024, ipw + (size_t)1024 * 1024, 1024, ipb + 1024, XK, 256, 1024);
  proj_vt_k<<<dim3(16, 4, 2), 256, 0, stream>>>(
      ipw + (size_t)1280 * 1024, value, ipb + 1280, XVt);

  // scores + sigmoid + clip -> q = 1-p (group-diagonal layout)
  scores_mfma_k<<<dim3(16, 16, 32), 256, 0, stream>>>(XQ, XK, P);

  // monotonic recurrence in place (restrict-split read/write views of P;
  // runtime disjointness guaranteed by the wrap bijection)
  mono_rec_k<<<dim3(32), dim3(64), 0, stream>>>(P, P);

  // phi @ V -> XO (NT against transposed V; A read through diagonal map)
  pv_mfma_k<<<dim3(1, 16, 32), 256, 0, stream>>>(P, XVt, XO);

  // out-projection
  gemm_nt_mfma_k<<<dim3(16, 32), 256, 0, stream>>>(
      XO, 1024, opw, 1024, opb, out, 1024, 1024);
}